// Round 8
// baseline (253.502 us; speedup 1.0000x reference)
//
#include <hip/hip_runtime.h>
#include <hip/hip_bf16.h>

#define B_ 2
#define C_ 512
#define H_ 50
#define W_ 75
#define N_ 2000
#define SS (1.0f/16.0f)

#define SB (H_ * W_ * C_)   // batch stride (elements), NHWC
#define SH (W_ * C_)        // row stride
#define SW (C_)             // col stride

// lgkm-only barrier: orders LDS traffic across the workgroup WITHOUT
// draining global loads/stores.
#define BAR_LGKM() asm volatile("s_waitcnt lgkmcnt(0)\n\ts_barrier" ::: "memory")

typedef unsigned short ushortx8 __attribute__((ext_vector_type(8)));
typedef float floatx4 __attribute__((ext_vector_type(4)));  // clang vector:
// __builtin_nontemporal_store rejects HIP_vector_type<float,4> (struct)

__device__ __forceinline__ float bf2f(unsigned short u) {
    union { unsigned i; float f; } c; c.i = (unsigned)u << 16; return c.f;
}

// fused transpose+convert: (B,C,H,W) fp32 -> (B,H,W,C) bf16
// 64-channel tile, packed bf16x2 stores (4B/lane).
__global__ __launch_bounds__(256) void transcvt_k2(const float* __restrict__ in,
                                                   __hip_bfloat16* __restrict__ out) {
    __shared__ float tile[64][33];
    const int b   = blockIdx.z;
    const int hw0 = blockIdx.x * 32;
    const int c0  = blockIdx.y * 64;
    const int tx  = threadIdx.x;   // 0..31
    const int ty  = threadIdx.y;   // 0..7
    const int hw  = hw0 + tx;
    if (hw < H_ * W_) {
        #pragma unroll
        for (int rr = 0; rr < 8; ++rr) {
            const int c = c0 + rr * 8 + ty;
            tile[rr * 8 + ty][tx] = in[(b * C_ + c) * (H_ * W_) + hw];
        }
    }
    __syncthreads();
    const int c2 = 2 * tx;
    #pragma unroll
    for (int rr = 0; rr < 4; ++rr) {
        const int hwl = rr * 8 + ty;
        const int hww = hw0 + hwl;
        if (hww < H_ * W_) {
            const __hip_bfloat16 lo = __float2bfloat16(tile[c2][hwl]);
            const __hip_bfloat16 hi = __float2bfloat16(tile[c2 + 1][hwl]);
            union { unsigned short u[2]; unsigned v; } pk;
            pk.u[0] = *(const unsigned short*)&lo;
            pk.u[1] = *(const unsigned short*)&hi;
            *(unsigned*)&out[((size_t)b * (H_ * W_) + hww) * C_ + c0 + c2] = pk.v;
        }
    }
}

// v9 = v8 (chunk=bid&7 XCD-pinned slices, ushort8 gather, stride-65
// channel-major sval, NT stores) +
//  - PER-LANE setup: j = wv*2+k, i = q are lane-position functions, so each
//    thread computes its own 2 (weight, offset) pairs from uniform rois
//    (s_loads). Removes the 64-thread setup phase, barrier #1, swt/soff LDS
//    arrays, and their reads in the gather.
//  - 0.25 pooling factor folded into vz (exact pow2 scale, bitwise-identical).
//  - reduce: 3 contiguous float4 NT-store rounds (1KB/wave-inst) + 16-thread
//    tail; store insts/thread 13 -> ~3; o/49 via magic (o*5350)>>18 (exact
//    o<43k), ji/7 via (ji*147)>>10 (exact ji<=48).
__global__ __launch_bounds__(256) void roi_avg_v9(
    const __hip_bfloat16* __restrict__ ftb, const float* __restrict__ rois,
    float* __restrict__ out)
{
    __shared__ float sval[64 * 65];   // [chan-in-chunk][sample], stride 65

    const int bid   = blockIdx.x;
    const int chunk = bid & 7;        // pinned to XCD by dispatch round-robin
    const int n     = bid >> 3;
    const int tid   = threadIdx.x;

    const int lane = tid & 63;
    const int wv   = tid >> 6;
    const int q    = lane >> 3;       // sample col i (0..7)
    const int l    = lane & 7;        // channel-octet index
    const int cl   = l * 8;           // channel within chunk (0..56)

    // uniform roi params -> scalar loads
    const float bfv = rois[n * 5 + 0];
    const float x1 = rois[n * 5 + 1] * SS;
    const float y1 = rois[n * 5 + 2] * SS;
    const float x2 = rois[n * 5 + 3] * SS;
    const float y2 = rois[n * 5 + 4] * SS;
    const int b = (int)bfv;
    const float roi_w = fmaxf(x2 - x1 + 1.0f, 0.0f);
    const float roi_h = fmaxf(y2 - y1 + 1.0f, 0.0f);
    const float bh = roi_h / 7.0f;
    const float bw = roi_w / 7.0f;

    // column (i = q) terms, shared by both k iterations
    const float w = x1 + (float)q * bw;
    const bool wok = (w >= 0.0f) && (w < (float)W_);
    int ws = (int)floorf(w); ws = ws < 0 ? 0 : (ws > W_ - 2 ? W_ - 2 : ws);
    const float wr = w - (float)ws;

    const unsigned short* const ft = (const unsigned short*)ftb;
    const int cbase = chunk * 64 + cl;

    #pragma unroll
    for (int k = 0; k < 2; ++k) {
        const int j = wv * 2 + k;                 // sample row
        const int s = j * 8 + q;
        const float h = y1 + (float)j * bh;
        const bool valid = wok && (h >= 0.0f) && (h < (float)H_);
        int hs = (int)floorf(h); hs = hs < 0 ? 0 : (hs > H_ - 2 ? H_ - 2 : hs);
        const float hr = h - (float)hs;
        const float vz = valid ? 0.25f : 0.0f;    // fold pooling 0.25 (exact)
        const float wx = (1.0f - hr) * (1.0f - wr) * vz;
        const float wy = (1.0f - hr) * wr * vz;
        const float wz = hr * (1.0f - wr) * vz;
        const float ww = hr * wr * vz;
        const unsigned short* p = ft + (b * SB + hs * SH + ws * SW + cbase);
        const ushortx8 a  = *(const ushortx8*)(p);
        const ushortx8 bq = *(const ushortx8*)(p + SW);
        const ushortx8 c  = *(const ushortx8*)(p + SH);
        const ushortx8 d  = *(const ushortx8*)(p + SH + SW);
        #pragma unroll
        for (int e = 0; e < 8; ++e) {
            // channel-major scatter; bank = (8l+e+s)%32 -> each bank exactly
            // 2x across the wave (free); e-stride 65 -> ds_write2_b32 pairs
            sval[(cl + e) * 65 + s] =
                bf2f(a[e]) * wx + bf2f(bq[e]) * wy +
                bf2f(c[e]) * wz + bf2f(d[e]) * ww;
        }
    }
    BAR_LGKM();

    const int out_base = n * (C_ * 49) + chunk * (64 * 49);
    // 3 full rounds of contiguous float4 stores (3072 outputs) + 64 tail
    #pragma unroll
    for (int m = 0; m < 3; ++m) {
        const int o0 = m * 1024 + 4 * tid;
        floatx4 v;
        #pragma unroll
        for (int e = 0; e < 4; ++e) {
            const int o  = o0 + e;
            const int c  = (o * 5350) >> 18;      // o/49
            const int ji = o - c * 49;
            const int jj = (ji * 147) >> 10;      // ji/7
            const int s  = ji + jj;               // j*8+i
            const float* sv = &sval[c * 65 + s];
            v[e] = ((sv[0] + sv[1]) + sv[8]) + sv[9];
        }
        __builtin_nontemporal_store(v, (floatx4*)&out[out_base + o0]);
    }
    if (tid < 16) {
        const int o0 = 3072 + 4 * tid;
        floatx4 v;
        #pragma unroll
        for (int e = 0; e < 4; ++e) {
            const int o  = o0 + e;
            const int c  = (o * 5350) >> 18;
            const int ji = o - c * 49;
            const int jj = (ji * 147) >> 10;
            const int s  = ji + jj;
            const float* sv = &sval[c * 65 + s];
            v[e] = ((sv[0] + sv[1]) + sv[8]) + sv[9];
        }
        __builtin_nontemporal_store(v, (floatx4*)&out[out_base + o0]);
    }
}

// Fallback: fp32 native-layout version (only if ws too small)
__global__ __launch_bounds__(256) void roi_avg_generic(
    const float* __restrict__ ft, const float* __restrict__ rois,
    float* __restrict__ out, int sB, int sH, int sW, int sC)
{
    __shared__ float  sval[64 * 65];
    __shared__ float4 swt[64];
    __shared__ int    soff[64];
    const int n   = blockIdx.x;
    const int tid = threadIdx.x;
    if (tid < 64) {
        const int s = tid;
        const int j = s >> 3;
        const int i = s & 7;
        const float bfv = rois[n * 5 + 0];
        const float x1 = rois[n * 5 + 1] * SS;
        const float y1 = rois[n * 5 + 2] * SS;
        const float x2 = rois[n * 5 + 3] * SS;
        const float y2 = rois[n * 5 + 4] * SS;
        const int b = (int)bfv;
        const float roi_w = fmaxf(x2 - x1 + 1.0f, 0.0f);
        const float roi_h = fmaxf(y2 - y1 + 1.0f, 0.0f);
        const float h = y1 + (float)j * (roi_h / 7.0f);
        const float w = x1 + (float)i * (roi_w / 7.0f);
        const bool valid = (h >= 0.0f) && (h < (float)H_) && (w >= 0.0f) && (w < (float)W_);
        int hs = (int)floorf(h); hs = hs < 0 ? 0 : (hs > H_ - 2 ? H_ - 2 : hs);
        int ws = (int)floorf(w); ws = ws < 0 ? 0 : (ws > W_ - 2 ? W_ - 2 : ws);
        const float hr = h - (float)hs;
        const float wr = w - (float)ws;
        const float vz = valid ? 1.0f : 0.0f;
        float4 wt;
        wt.x = (1.0f - hr) * (1.0f - wr) * vz;
        wt.y = (1.0f - hr) * wr * vz;
        wt.z = hr * (1.0f - wr) * vz;
        wt.w = hr * wr * vz;
        swt[s]  = wt;
        soff[s] = b * sB + hs * sH + ws * sW;
    }
    __syncthreads();
    const int lane = tid & 63;
    const int wv   = tid >> 6;
    for (int chunk = 0; chunk < C_ / 64; ++chunk) {
        const int cbase = (chunk * 64 + lane) * sC;
        #pragma unroll 4
        for (int k = 0; k < 16; ++k) {
            const int s = wv * 16 + k;
            const float4 wt = swt[s];
            const int off = soff[s] + cbase;
            sval[lane * 65 + s] = ft[off]            * wt.x + ft[off + sW]      * wt.y +
                                  ft[off + sH]       * wt.z + ft[off + sH + sW] * wt.w;
        }
        __syncthreads();
        const int out_base = n * (C_ * 49) + chunk * (64 * 49);
        #pragma unroll
        for (int r = 0; r < 13; ++r) {
            const int o = r * 256 + tid;
            if (o < 64 * 49) {
                const int c  = o / 49;
                const int ji = o - c * 49;
                const int jj = ji / 7;
                const int s  = ji + jj;
                const float* sv = &sval[c * 65 + s];
                out[out_base + o] = 0.25f * (sv[0] + sv[1] + sv[8] + sv[9]);
            }
        }
        __syncthreads();
    }
}

extern "C" void kernel_launch(void* const* d_in, const int* in_sizes, int n_in,
                              void* d_out, int out_size, void* d_ws, size_t ws_size,
                              hipStream_t stream) {
    const float* features = (const float*)d_in[0];
    const float* rois     = (const float*)d_in[1];
    float* out            = (float*)d_out;

    const size_t need = (size_t)B_ * C_ * H_ * W_ * sizeof(__hip_bfloat16);
    if (ws_size >= need) {
        __hip_bfloat16* ftb = (__hip_bfloat16*)d_ws;
        dim3 g((H_ * W_ + 31) / 32, C_ / 64, B_);
        dim3 b(32, 8, 1);
        transcvt_k2<<<g, b, 0, stream>>>(features, ftb);
        roi_avg_v9<<<N_ * 8, 256, 0, stream>>>(ftb, rois, out);
    } else {
        roi_avg_generic<<<N_, 256, 0, stream>>>(features, rois, out,
                                                C_ * H_ * W_, W_, 1, H_ * W_);
    }
}

// Round 9
// 222.312 us; speedup vs baseline: 1.1403x; 1.1403x over previous
//
#include <hip/hip_runtime.h>
#include <hip/hip_bf16.h>

#define B_ 2
#define C_ 512
#define H_ 50
#define W_ 75
#define N_ 2000
#define SS (1.0f/16.0f)

#define SB (H_ * W_ * C_)   // batch stride (elements), NHWC
#define SH (W_ * C_)        // row stride
#define SW (C_)             // col stride

// lgkm-only barrier: orders LDS traffic across the workgroup WITHOUT
// draining global loads/stores.
#define BAR_LGKM() asm volatile("s_waitcnt lgkmcnt(0)\n\ts_barrier" ::: "memory")

typedef unsigned short ushortx8 __attribute__((ext_vector_type(8)));

__device__ __forceinline__ float bf2f(unsigned short u) {
    union { unsigned i; float f; } c; c.i = (unsigned)u << 16; return c.f;
}

// fused transpose+convert: (B,C,H,W) fp32 -> (B,H,W,C) bf16
// 64-channel tile, packed bf16x2 stores (4B/lane).
__global__ __launch_bounds__(256) void transcvt_k2(const float* __restrict__ in,
                                                   __hip_bfloat16* __restrict__ out) {
    __shared__ float tile[64][33];
    const int b   = blockIdx.z;
    const int hw0 = blockIdx.x * 32;
    const int c0  = blockIdx.y * 64;
    const int tx  = threadIdx.x;   // 0..31
    const int ty  = threadIdx.y;   // 0..7
    const int hw  = hw0 + tx;
    if (hw < H_ * W_) {
        #pragma unroll
        for (int rr = 0; rr < 8; ++rr) {
            const int c = c0 + rr * 8 + ty;
            tile[rr * 8 + ty][tx] = in[(b * C_ + c) * (H_ * W_) + hw];
        }
    }
    __syncthreads();
    const int c2 = 2 * tx;
    #pragma unroll
    for (int rr = 0; rr < 4; ++rr) {
        const int hwl = rr * 8 + ty;
        const int hww = hw0 + hwl;
        if (hww < H_ * W_) {
            const __hip_bfloat16 lo = __float2bfloat16(tile[c2][hwl]);
            const __hip_bfloat16 hi = __float2bfloat16(tile[c2 + 1][hwl]);
            union { unsigned short u[2]; unsigned v; } pk;
            pk.u[0] = *(const unsigned short*)&lo;
            pk.u[1] = *(const unsigned short*)&hi;
            *(unsigned*)&out[((size_t)b * (H_ * W_) + hww) * C_ + c0 + c2] = pk.v;
        }
    }
}

// v10 = v8 (best measured: 223.2us) + 0.25 pooling factor folded into the
// bilinear weights at setup (vz = 0.25 instead of 1.0). Pow2 scaling
// commutes with RNE rounding through the whole mul/add chain -> output
// bitwise identical; kills one v_mul per output in reduce.
// v9's bundle (per-lane setup + float4-store reduce) regressed +30us —
// float4 reduce forced lane s-stride-4 -> 8-way LDS read conflicts;
// reverted wholesale per ablate-by-revert discipline.
__global__ __launch_bounds__(256) void roi_avg_v10(
    const __hip_bfloat16* __restrict__ ftb, const float* __restrict__ rois,
    float* __restrict__ out)
{
    __shared__ float  sval[64 * 65];   // [chan-in-chunk][sample], stride 65
    __shared__ float4 swt[64];
    __shared__ int    soff[64];

    const int bid   = blockIdx.x;
    const int chunk = bid & 7;         // pinned to XCD by dispatch round-robin
    const int n     = bid >> 3;
    const int tid   = threadIdx.x;

    if (tid < 64) {
        const int s = tid;
        const int j = s >> 3;
        const int i = s & 7;
        const float bfv = rois[n * 5 + 0];
        const float x1 = rois[n * 5 + 1] * SS;
        const float y1 = rois[n * 5 + 2] * SS;
        const float x2 = rois[n * 5 + 3] * SS;
        const float y2 = rois[n * 5 + 4] * SS;
        const int b = (int)bfv;
        const float roi_w = fmaxf(x2 - x1 + 1.0f, 0.0f);
        const float roi_h = fmaxf(y2 - y1 + 1.0f, 0.0f);
        const float h = y1 + (float)j * (roi_h / 7.0f);
        const float w = x1 + (float)i * (roi_w / 7.0f);
        const bool valid = (h >= 0.0f) && (h < (float)H_) &&
                           (w >= 0.0f) && (w < (float)W_);
        int hs = (int)floorf(h); hs = hs < 0 ? 0 : (hs > H_ - 2 ? H_ - 2 : hs);
        int ws = (int)floorf(w); ws = ws < 0 ? 0 : (ws > W_ - 2 ? W_ - 2 : ws);
        const float hr = h - (float)hs;
        const float wr = w - (float)ws;
        const float vz = valid ? 0.25f : 0.0f;   // fold pooling 0.25 (exact)
        float4 wt;
        wt.x = (1.0f - hr) * (1.0f - wr) * vz;
        wt.y = (1.0f - hr) * wr * vz;
        wt.z = hr * (1.0f - wr) * vz;
        wt.w = hr * wr * vz;
        swt[s]  = wt;
        soff[s] = b * SB + hs * SH + ws * SW;
    }
    BAR_LGKM();

    const unsigned short* const ft = (const unsigned short*)ftb;
    const int lane = tid & 63;
    const int wv   = tid >> 6;
    const int q    = lane >> 3;        // sample sub-index 0..7
    const int l    = lane & 7;         // channel-octet index
    const int cl   = l * 8;            // channel within chunk (0..56)

    const int cbase = chunk * 64 + cl;
    #pragma unroll
    for (int k = 0; k < 2; ++k) {
        const int s = wv * 16 + k * 8 + q;
        const float4 wt = swt[s];
        const unsigned short* p = ft + soff[s] + cbase;   // 16B-aligned
        const ushortx8 a  = *(const ushortx8*)(p);
        const ushortx8 bq = *(const ushortx8*)(p + SW);
        const ushortx8 c  = *(const ushortx8*)(p + SH);
        const ushortx8 d  = *(const ushortx8*)(p + SH + SW);
        #pragma unroll
        for (int e = 0; e < 8; ++e) {
            // channel-major scatter; bank = (8l+e+s)%32 -> each bank exactly
            // 2x across the wave (free); e-stride 65 -> ds_write2_b32 pairs
            sval[(cl + e) * 65 + s] =
                bf2f(a[e])  * wt.x + bf2f(bq[e]) * wt.y +
                bf2f(c[e])  * wt.z + bf2f(d[e])  * wt.w;
        }
    }
    BAR_LGKM();

    const int out_base = n * (C_ * 49) + chunk * (64 * 49);
    #pragma unroll
    for (int r = 0; r < 13; ++r) {
        const int o = r * 256 + tid;
        if (o < 64 * 49) {
            const int c  = o / 49;       // chan-in-chunk, ~fixed across a wave
            const int ji = o - c * 49;
            const int jj = ji / 7;
            const int s  = ji + jj;      // j*8+i == (j*7+i)+j
            const float* sv = &sval[c * 65 + s];
            // (sv[0],sv[1]) and (sv[8],sv[9]) -> ds_read2_b32, s-stride-1
            const float v = (sv[0] + sv[1]) + (sv[8] + sv[9]);  // 0.25 pre-folded
            __builtin_nontemporal_store(v, &out[out_base + o]);  // stream past L2
        }
    }
}

// Fallback: fp32 native-layout version (only if ws too small)
__global__ __launch_bounds__(256) void roi_avg_generic(
    const float* __restrict__ ft, const float* __restrict__ rois,
    float* __restrict__ out, int sB, int sH, int sW, int sC)
{
    __shared__ float  sval[64 * 65];
    __shared__ float4 swt[64];
    __shared__ int    soff[64];
    const int n   = blockIdx.x;
    const int tid = threadIdx.x;
    if (tid < 64) {
        const int s = tid;
        const int j = s >> 3;
        const int i = s & 7;
        const float bfv = rois[n * 5 + 0];
        const float x1 = rois[n * 5 + 1] * SS;
        const float y1 = rois[n * 5 + 2] * SS;
        const float x2 = rois[n * 5 + 3] * SS;
        const float y2 = rois[n * 5 + 4] * SS;
        const int b = (int)bfv;
        const float roi_w = fmaxf(x2 - x1 + 1.0f, 0.0f);
        const float roi_h = fmaxf(y2 - y1 + 1.0f, 0.0f);
        const float h = y1 + (float)j * (roi_h / 7.0f);
        const float w = x1 + (float)i * (roi_w / 7.0f);
        const bool valid = (h >= 0.0f) && (h < (float)H_) && (w >= 0.0f) && (w < (float)W_);
        int hs = (int)floorf(h); hs = hs < 0 ? 0 : (hs > H_ - 2 ? H_ - 2 : hs);
        int ws = (int)floorf(w); ws = ws < 0 ? 0 : (ws > W_ - 2 ? W_ - 2 : ws);
        const float hr = h - (float)hs;
        const float wr = w - (float)ws;
        const float vz = valid ? 1.0f : 0.0f;
        float4 wt;
        wt.x = (1.0f - hr) * (1.0f - wr) * vz;
        wt.y = (1.0f - hr) * wr * vz;
        wt.z = hr * (1.0f - wr) * vz;
        wt.w = hr * wr * vz;
        swt[s]  = wt;
        soff[s] = b * sB + hs * sH + ws * sW;
    }
    __syncthreads();
    const int lane = tid & 63;
    const int wv   = tid >> 6;
    for (int chunk = 0; chunk < C_ / 64; ++chunk) {
        const int cbase = (chunk * 64 + lane) * sC;
        #pragma unroll 4
        for (int k = 0; k < 16; ++k) {
            const int s = wv * 16 + k;
            const float4 wt = swt[s];
            const int off = soff[s] + cbase;
            sval[lane * 65 + s] = ft[off]            * wt.x + ft[off + sW]      * wt.y +
                                  ft[off + sH]       * wt.z + ft[off + sH + sW] * wt.w;
        }
        __syncthreads();
        const int out_base = n * (C_ * 49) + chunk * (64 * 49);
        #pragma unroll
        for (int r = 0; r < 13; ++r) {
            const int o = r * 256 + tid;
            if (o < 64 * 49) {
                const int c  = o / 49;
                const int ji = o - c * 49;
                const int jj = ji / 7;
                const int s  = ji + jj;
                const float* sv = &sval[c * 65 + s];
                out[out_base + o] = 0.25f * (sv[0] + sv[1] + sv[8] + sv[9]);
            }
        }
        __syncthreads();
    }
}

extern "C" void kernel_launch(void* const* d_in, const int* in_sizes, int n_in,
                              void* d_out, int out_size, void* d_ws, size_t ws_size,
                              hipStream_t stream) {
    const float* features = (const float*)d_in[0];
    const float* rois     = (const float*)d_in[1];
    float* out            = (float*)d_out;

    const size_t need = (size_t)B_ * C_ * H_ * W_ * sizeof(__hip_bfloat16);
    if (ws_size >= need) {
        __hip_bfloat16* ftb = (__hip_bfloat16*)d_ws;
        dim3 g((H_ * W_ + 31) / 32, C_ / 64, B_);
        dim3 b(32, 8, 1);
        transcvt_k2<<<g, b, 0, stream>>>(features, ftb);
        roi_avg_v10<<<N_ * 8, 256, 0, stream>>>(ftb, rois, out);
    } else {
        roi_avg_generic<<<N_, 256, 0, stream>>>(features, rois, out,
                                                C_ * H_ * W_, W_, 1, H_ * W_);
    }
}